// Round 9
// baseline (149.053 us; speedup 1.0000x reference)
//
#include <hip/hip_runtime.h>
#include <cstdint>

#define T_DIM 1000
#define B_DIM 64
#define C_DIM 256
#define L_DIM 100
#define S_DIM (2 * L_DIM + 1) /* 201 */
#define CH 32                 /* steps per chunk */
#define NPROD 7               /* producer waves (block = 8 waves) */
#define RPW 5                 /* ceil(CH/NPROD) rows per producer wave */

typedef float f32x4 __attribute__((ext_vector_type(4)));

// DPP cross-lane (VALU-rate). wave_shr:1=0x138, row_shr:n=0x110|n,
// row_bcast:15=0x142, row_bcast:31=0x143. bound_ctrl=true -> invalid lanes read 0.
#define DPP_I(x, ctrl) __builtin_amdgcn_update_dpp(0, (x), (ctrl), 0xF, 0xF, true)
#define DPP_F(x, ctrl) __int_as_float(DPP_I(__float_as_int(x), (ctrl)))

// Producer staging rules (R6/R7): compiler loads only (sound waits);
// ONE asm anchoring all 5 float4s -> batch issue, single drain, no remat.
// Consumer LDS reads: R4 inline-asm ds_read + counted lgkmcnt (proven
// bit-identical, neutral -- kept).
#define DSR(dst, addr, OFF) \
    asm volatile("ds_read_b32 %0, %1 offset:" OFF : "=v"(dst) : "v"(addr))
#define ISS(s, OFF) do { DSR(pb##s, apb, OFF); DSR(qa##s, aq1, OFF); DSR(qb##s, aq3, OFF); } while (0)
#define W(N) do { asm volatile("s_waitcnt lgkmcnt(" N ")"); __builtin_amdgcn_sched_barrier(0); } while (0)
#define STP(s) step(pb##s, qa##s, qb##s)

// Wave-wide max of non-negative values; exact, order-independent.
__device__ __forceinline__ float wave_max_dpp(float x) {
    x = fmaxf(x, DPP_F(x, 0x111)); // row_shr:1
    x = fmaxf(x, DPP_F(x, 0x112)); // row_shr:2
    x = fmaxf(x, DPP_F(x, 0x114)); // row_shr:4
    x = fmaxf(x, DPP_F(x, 0x118)); // row_shr:8
    x = fmaxf(x, DPP_F(x, 0x142)); // row_bcast:15
    x = fmaxf(x, DPP_F(x, 0x143)); // row_bcast:31 -> lane 63 has wave max
    return __int_as_float(__builtin_amdgcn_readlane(__float_as_int(x), 63));
}

// R8: mean pass split into its OWN kernel (rocprof finally shows t_ctc and
// t_mean separately -- 8 rounds of neutral scheduling fixes mean the fused
// dispatch's 54us was never attributable). Redesigned: 512 blocks = (b, 8
// T-slices of 125 rows), 256 threads (4 waves). Wave w covers rows t0+w,
// t0+w+4, ...; lane l loads f32x4 at channel 4l (COALESCED 1KB/wave/row,
// 4x fewer load instrs than scalar). LDS cross-wave reduce; 256 atomicAdds
// per block (8 per (b,c) address total).
__global__ __launch_bounds__(256) void mean_pass(
        const float* __restrict__ lp, float* __restrict__ ws_mean) {
    const int mb = blockIdx.x;
    const int b = mb >> 3;
    const int t0 = (mb & 7) * 125;
    const int lane = threadIdx.x & 63;
    const int wv = threadIdx.x >> 6;           // 0..3
    const uint32_t rstride = B_DIM * C_DIM;
    const float* p = lp + (size_t)b * C_DIM + (lane << 2);
    f32x4 s = {0.f, 0.f, 0.f, 0.f};
    for (int t = t0 + wv; t < t0 + 125; t += 4) {
        f32x4 v = *(const f32x4*)(p + (size_t)t * rstride);
        s.x += __expf(v.x); s.y += __expf(v.y);
        s.z += __expf(v.z); s.w += __expf(v.w);
    }
    __shared__ float sums[4][C_DIM];
    *(f32x4*)&sums[wv][lane << 2] = s;
    __syncthreads();
    const int c = threadIdx.x;                  // 0..255
    const float tot = sums[0][c] + sums[1][c] + sums[2][c] + sums[3][c];
    atomicAdd(&ws_mean[b * C_DIM + c], tot * (1.0f / T_DIM));
}

// CTC kernel: 64 blocks x 512 threads. Internals BYTE-IDENTICAL to R7's CTC
// path (mean branch deleted) for clean attribution of its dispatch time.
__global__ __launch_bounds__(512, 1) void ctc_fused(
        const float* __restrict__ lp,       // (T,B,C)
        const int* __restrict__ tgt,        // (B*L,)
        const int* __restrict__ il,         // (B,)
        const int* __restrict__ tl,         // (B,)
        float* __restrict__ ws_loss) {      // (B,)
    const int blk = blockIdx.x;
    const uint32_t rstride = B_DIM * C_DIM;

    __shared__ __align__(16) float rows[2][CH][C_DIM]; // exp'd rows, 64 KB

    const int tid = threadIdx.x;
    const int lane = tid & 63;
    const int wave = tid >> 6;
    const int b = blk;
    const int* trow = tgt + b * L_DIM;
    const int ilen = il[b];
    const int tlen = tl[b];

    const int i1 = 2 * lane;
    const int i3 = 2 * lane + 1;
    const int c1 = (i1 < L_DIM) ? trow[i1] : 0;
    const int c3 = (i3 < L_DIM) ? trow[i3] : 0;
    const int c1m = (i1 >= 1 && i1 - 1 < L_DIM) ? trow[i1 - 1] : -1;
    const float m1 = ((i1 >= 1) && (c1 != c1m)) ? 1.0f : 0.0f;
    const float m3 = (c3 != c1) ? 1.0f : 0.0f;

    // invalid states (s >= S) must be zeroed at each renorm
    const float f0 = (4 * lane + 0 < S_DIM) ? 1.0f : 0.0f;
    const float f1 = (4 * lane + 1 < S_DIM) ? 1.0f : 0.0f;
    const float f2 = (4 * lane + 2 < S_DIM) ? 1.0f : 0.0f;
    const float f3 = (4 * lane + 3 < S_DIM) ? 1.0f : 0.0f;

    const float* base = lp + (size_t)b * C_DIM;

    // t=0 init (bit-identical)
    float a0 = 0.f, a1 = 0.f, a2 = 0.f, a3 = 0.f;
    {
        float i0 = __expf(base[0]);
        float i1v = __expf(base[c1]);
        if (lane == 0 && wave == 0) { a0 = i0; a1 = i1v; }
    }
    float ls = 0.f;

    // producer: 5 coalesced COMPILER loads, one anchor, one drain; exp whole
    // rows + ping-pong LDS store. Values bit-identical to baseline.
    auto produce = [&](int cc) {
        const int p = cc & 1;
        const int tstart = 1 + cc * CH;
        f32x4 v[RPW];
#pragma unroll
        for (int k = 0; k < RPW; ++k) {
            const int d = (wave - 1) + NPROD * k;
            if (d < CH) {
                int t = tstart + d; t = (t < ilen) ? t : (ilen - 1);
                v[k] = *(const f32x4*)(base + (size_t)t * rstride + (lane << 2));
            } else {
                v[k] = (f32x4){0.f, 0.f, 0.f, 0.f};
            }
        }
        asm volatile("" : "+v"(v[0]), "+v"(v[1]), "+v"(v[2]), "+v"(v[3]), "+v"(v[4]));
#pragma unroll
        for (int k = 0; k < RPW; ++k) {
            const int d = (wave - 1) + NPROD * k;
            if (d < CH) {
                f32x4 e;
                e.x = __expf(v[k].x); e.y = __expf(v[k].y);
                e.z = __expf(v[k].z); e.w = __expf(v[k].w);
                *(f32x4*)&rows[p][d][lane << 2] = e;
            }
        }
    };

    // consumer step: inputs already exp'd; absmax must stay 96.0.
    auto step = [&](float pb, float p1e, float p3e) {
        const float p3 = DPP_F(a3, 0x138); // prev lane's a3; lane0 -> 0
        const float a01 = a0 + a1;
        const float n0 = (a0 + p3) * pb;
        const float n1 = fmaf(m1, p3, a01) * p1e;
        const float n2 = (a2 + a1) * pb;
        const float n3 = (fmaf(m3, a1, a2) + a3) * p3e;
        a0 = n0; a1 = n1; a2 = n2; a3 = n3;
    };

#define RENORM() do {                                                       \
        a0 *= f0; a1 *= f1; a2 *= f2; a3 *= f3;                             \
        const float mx = wave_max_dpp(fmaxf(fmaxf(a0, a1), fmaxf(a2, a3))); \
        const float inv = __builtin_amdgcn_rcpf(mx);                        \
        ls -= __logf(inv);                                                  \
        a0 *= inv; a1 *= inv; a2 *= inv; a3 *= inv;                         \
    } while (0)

    // consume chunk cc; renorms after d=7,15,23,31 (baseline set; tail none).
    auto consume = [&](int cc) {
        const int p = cc & 1;
        const int tstart = 1 + cc * CH;
        if (tstart + CH <= ilen) {
            const uint32_t lbase =
                (uint32_t)(uintptr_t)(&rows[0][0][0]) + (uint32_t)(p * (CH * C_DIM * 4));
            uint32_t apb = lbase;                          // rows[p][d][0]
            uint32_t aq1 = lbase + ((uint32_t)c1 << 2);    // rows[p][d][c1]
            uint32_t aq3 = lbase + ((uint32_t)c3 << 2);    // rows[p][d][c3]
            float pb0, pb1, pb2, pb3, pb4;
            float qa0, qa1, qa2, qa3, qa4;
            float qb0, qb1, qb2, qb3, qb4;
            ISS(0, "0"); ISS(1, "1024"); ISS(2, "2048"); ISS(3, "3072"); ISS(4, "4096");
            W("12"); STP(0); ISS(0, "5120");                 // d=0
            W("12"); STP(1); ISS(1, "6144");                 // d=1
            W("12"); STP(2); ISS(2, "7168");                 // d=2
            W("12"); STP(3); ISS(3, "8192");                 // d=3
            W("12"); STP(4); ISS(4, "9216");                 // d=4
            W("12"); STP(0); ISS(0, "10240");                // d=5
            W("12"); STP(1); ISS(1, "11264");                // d=6
            W("12"); STP(2); ISS(2, "12288"); RENORM();      // d=7
            W("12"); STP(3); ISS(3, "13312");                // d=8
            W("12"); STP(4); ISS(4, "14336");                // d=9
            W("12"); STP(0); ISS(0, "15360");                // d=10
            W("12"); STP(1); ISS(1, "16384");                // d=11
            W("12"); STP(2); ISS(2, "17408");                // d=12
            W("12"); STP(3); ISS(3, "18432");                // d=13
            W("12"); STP(4); ISS(4, "19456");                // d=14
            W("12"); STP(0); ISS(0, "20480"); RENORM();      // d=15
            W("12"); STP(1); ISS(1, "21504");                // d=16
            W("12"); STP(2); ISS(2, "22528");                // d=17
            W("12"); STP(3); ISS(3, "23552");                // d=18
            W("12"); STP(4); ISS(4, "24576");                // d=19
            W("12"); STP(0); ISS(0, "25600");                // d=20
            W("12"); STP(1); ISS(1, "26624");                // d=21
            W("12"); STP(2); ISS(2, "27648");                // d=22
            W("12"); STP(3); ISS(3, "28672"); RENORM();      // d=23
            W("12"); STP(4); ISS(4, "29696");                // d=24
            W("12"); STP(0); ISS(0, "30720");                // d=25
            W("12"); STP(1); ISS(1, "31744");                // d=26 (issues d=31)
            W("12"); STP(2);                                 // d=27
            W("9");  STP(3);                                 // d=28
            W("6");  STP(4);                                 // d=29
            W("3");  STP(0);                                 // d=30
            W("0");  STP(1); RENORM();                       // d=31
        } else {
            // tail chunk (7 steps for T=1000): baseline point-of-use form
#pragma unroll
            for (int d = 0; d < CH; ++d) {
                if (tstart + d < ilen) {
                    step(rows[p][d][0], rows[p][d][c1], rows[p][d][c3]);
                    if ((d & 7) == 7) RENORM();
                }
            }
        }
    };

    const int nchunks = (ilen - 1 + CH - 1) / CH;
    if (wave != 0) produce(0);
    __syncthreads();
    if (wave == 0) __builtin_amdgcn_s_setprio(1); // consumer is the critical chain
    for (int c = 0; c < nchunks; ++c) {
        if (wave != 0) produce(c + 1); // other parity; last iter clamped junk, never read
        else consume(c);
        __syncthreads();
    }
    if (wave == 0) __builtin_amdgcn_s_setprio(0);
#undef RENORM

    if (wave != 0) return;

    // final: ll = log(alpha[2tl] + alpha[2tl-1]) + ls   (consumer wave only)
    const int s_hi = 2 * tlen;
    const int s_lo = 2 * tlen - 1;
    const int slot_hi = s_hi & 3, lane_hi = min(s_hi >> 2, 63);
    const int slot_lo = s_lo & 3, lane_lo = min(s_lo >> 2, 63);
    float ch = (slot_hi == 0) ? a0 : (slot_hi == 1) ? a1 : (slot_hi == 2) ? a2 : a3;
    float cl = (slot_lo == 0) ? a0 : (slot_lo == 1) ? a1 : (slot_lo == 2) ? a2 : a3;
    const float vh = __shfl(ch, lane_hi, 64);
    const float vl = __shfl(cl, lane_lo, 64);
    if (lane == 0) {
        const float s = vh + vl;
        const float loss = (s > 0.f) ? -(__logf(s) + ls) : 0.0f; // zero_infinity
        ws_loss[b] = loss;
    }
}

// out = (sum_j focal_j / (B*L)) * (sum_b loss_b / B)
__global__ __launch_bounds__(256) void ctc_finalize(
        const float* __restrict__ ws_mean, const float* __restrict__ ws_loss,
        const int* __restrict__ tgt, float* __restrict__ out) {
    const int tid = threadIdx.x;
    float fsum = 0.f;
#pragma unroll
    for (int k = 0; k < (B_DIM * L_DIM) / 256; ++k) {
        const int j = tid + k * 256;
        const int b = j / L_DIM;
        const int c = tgt[j];
        const float p = ws_mean[b * C_DIM + c];
        const float w = 1.0f - p;
        fsum += w * w;
    }
    float lsum = (tid < B_DIM) ? ws_loss[tid] : 0.f;
#pragma unroll
    for (int off = 32; off > 0; off >>= 1) {
        fsum += __shfl_down(fsum, off, 64);
        lsum += __shfl_down(lsum, off, 64);
    }
    __shared__ float sf[4], sl[4];
    const int w = tid >> 6;
    if ((tid & 63) == 0) { sf[w] = fsum; sl[w] = lsum; }
    __syncthreads();
    if (tid == 0) {
        const float F = sf[0] + sf[1] + sf[2] + sf[3];
        const float Lo = sl[0] + sl[1] + sl[2] + sl[3];
        out[0] = (F / (float)(B_DIM * L_DIM)) * (Lo / (float)B_DIM);
    }
}

extern "C" void kernel_launch(void* const* d_in, const int* in_sizes, int n_in,
                              void* d_out, int out_size, void* d_ws, size_t ws_size,
                              hipStream_t stream) {
    const float* lp = (const float*)d_in[0];
    const int* tgt = (const int*)d_in[1];
    const int* il = (const int*)d_in[2];
    const int* tl = (const int*)d_in[3];
    float* ws_mean = (float*)d_ws;               // B*C floats (atomicAdd target)
    float* ws_loss = ws_mean + B_DIM * C_DIM;    // B floats

    hipMemsetAsync(ws_mean, 0, B_DIM * C_DIM * sizeof(float), stream);
    mean_pass<<<dim3(B_DIM * 8), dim3(256), 0, stream>>>(lp, ws_mean);
    ctc_fused<<<dim3(B_DIM), dim3(512), 0, stream>>>(lp, tgt, il, tl, ws_loss);
    ctc_finalize<<<dim3(1), dim3(256), 0, stream>>>(ws_mean, ws_loss, tgt, (float*)d_out);
}

// Round 10
// 137.393 us; speedup vs baseline: 1.0849x; 1.0849x over previous
//
#include <hip/hip_runtime.h>
#include <cstdint>

#define T_DIM 1000
#define B_DIM 64
#define C_DIM 256
#define L_DIM 100
#define S_DIM (2 * L_DIM + 1) /* 201 */
#define CH 64                 /* steps per chunk (R9: was 32; halves per-chunk overhead) */
#define NPROD 7               /* producer waves (block = 8 waves) */
#define RPW 10                /* ceil(CH/NPROD) rows per producer wave */
#define MEAN_BLOCKS 192       /* 64 b x 3 T-slices; grid = 64+192 = 256 = #CUs */

typedef float f32x4 __attribute__((ext_vector_type(4)));

// DPP cross-lane (VALU-rate). wave_shr:1=0x138, row_shr:n=0x110|n,
// row_bcast:15=0x142, row_bcast:31=0x143. bound_ctrl=true -> invalid lanes read 0.
#define DPP_I(x, ctrl) __builtin_amdgcn_update_dpp(0, (x), (ctrl), 0xF, 0xF, true)
#define DPP_F(x, ctrl) __int_as_float(DPP_I(__float_as_int(x), (ctrl)))

// Producer staging rules (R6/R7): compiler loads only (sound waits);
// ONE asm anchoring all row regs -> batch issue, single drain, no remat.
// Consumer LDS reads: R4 inline-asm ds_read + counted lgkmcnt (bit-identical).
#define DSR(dst, addr, OFF) \
    asm volatile("ds_read_b32 %0, %1 offset:" OFF : "=v"(dst) : "v"(addr))
#define ISS(s, OFF) do { DSR(pb##s, apb, OFF); DSR(qa##s, aq1, OFF); DSR(qb##s, aq3, OFF); } while (0)
#define W(N) do { asm volatile("s_waitcnt lgkmcnt(" N ")"); __builtin_amdgcn_sched_barrier(0); } while (0)
#define STP(s) step(pb##s, qa##s, qb##s)
#define SD(s, OFF) do { W("12"); STP(s); ISS(s, OFF); } while (0)

// Wave-wide max of non-negative values; exact, order-independent.
__device__ __forceinline__ float wave_max_dpp(float x) {
    x = fmaxf(x, DPP_F(x, 0x111)); // row_shr:1
    x = fmaxf(x, DPP_F(x, 0x112)); // row_shr:2
    x = fmaxf(x, DPP_F(x, 0x114)); // row_shr:4
    x = fmaxf(x, DPP_F(x, 0x118)); // row_shr:8
    x = fmaxf(x, DPP_F(x, 0x142)); // row_bcast:15
    x = fmaxf(x, DPP_F(x, 0x143)); // row_bcast:31 -> lane 63 has wave max
    return __int_as_float(__builtin_amdgcn_readlane(__float_as_int(x), 63));
}

// Fused kernel, 512-thread blocks; grid = 256 = #CUs (1 block/CU).
// R9 finding: ctc-only dispatch = 52.5us regardless of HBM/L3 and of ANY
// instruction scheduling on either wave role -> cost is per-chunk phase
// overhead and/or low DVFS clock. This round: CH=64 (32 -> 16 chunks,
// halves barrier/phase/fill costs; LDS 128KB+8KB of 160KB). Renorm set
// {t%8==0, t<=992} PRESERVED EXACTLY -> bit-identical CTC numerics.
//   blocks [0,B): CTC alpha recursion (consumer wave 0 + 7 producers).
//   blocks [B, B+192): mean pass, f32x4-vectorized (R9 design, fused back
//     to overlap with ctc instead of serializing: R9 split cost +11us).
__global__ __launch_bounds__(512, 1) void ctc_fused(
        const float* __restrict__ lp,       // (T,B,C)
        const int* __restrict__ tgt,        // (B*L,)
        const int* __restrict__ il,         // (B,)
        const int* __restrict__ tl,         // (B,)
        float* __restrict__ ws_mean,        // (B,C) zero-initialized
        float* __restrict__ ws_loss) {      // (B,)
    const int blk = blockIdx.x;
    const uint32_t rstride = B_DIM * C_DIM;

    if (blk >= B_DIM) {
        // ---- mean pass: block=(b, slice of T in {336,336,328}); 8 waves ----
        __shared__ float sums[8][C_DIM];
        const int mb = blk - B_DIM;
        const int b = mb / 3;
        const int slice = mb % 3;
        const int start = slice * 336;
        const int end = (slice == 2) ? T_DIM : start + 336; // (end-start)%8==0
        const int lane = threadIdx.x & 63;
        const int wv = threadIdx.x >> 6;        // 0..7
        const float* p = lp + (size_t)b * C_DIM + (lane << 2);
        f32x4 s = {0.f, 0.f, 0.f, 0.f};
        for (int t = start + wv; t < end; t += 8) {
            f32x4 v = *(const f32x4*)(p + (size_t)t * rstride);
            s.x += __expf(v.x); s.y += __expf(v.y);
            s.z += __expf(v.z); s.w += __expf(v.w);
        }
        *(f32x4*)&sums[wv][lane << 2] = s;
        __syncthreads();
        if (threadIdx.x < C_DIM) {
            const int c = threadIdx.x;
            float tot = sums[0][c] + sums[1][c] + sums[2][c] + sums[3][c]
                      + sums[4][c] + sums[5][c] + sums[6][c] + sums[7][c];
            atomicAdd(&ws_mean[b * C_DIM + c], tot * (1.0f / T_DIM));
        }
        return;
    }

    // ---- CTC pass ----
    __shared__ __align__(16) float rows[2][CH][C_DIM]; // exp'd rows, 128 KB

    const int tid = threadIdx.x;
    const int lane = tid & 63;
    const int wave = tid >> 6;
    const int b = blk;
    const int* trow = tgt + b * L_DIM;
    const int ilen = il[b];
    const int tlen = tl[b];

    const int i1 = 2 * lane;
    const int i3 = 2 * lane + 1;
    const int c1 = (i1 < L_DIM) ? trow[i1] : 0;
    const int c3 = (i3 < L_DIM) ? trow[i3] : 0;
    const int c1m = (i1 >= 1 && i1 - 1 < L_DIM) ? trow[i1 - 1] : -1;
    const float m1 = ((i1 >= 1) && (c1 != c1m)) ? 1.0f : 0.0f;
    const float m3 = (c3 != c1) ? 1.0f : 0.0f;

    // invalid states (s >= S) must be zeroed at each renorm
    const float f0 = (4 * lane + 0 < S_DIM) ? 1.0f : 0.0f;
    const float f1 = (4 * lane + 1 < S_DIM) ? 1.0f : 0.0f;
    const float f2 = (4 * lane + 2 < S_DIM) ? 1.0f : 0.0f;
    const float f3 = (4 * lane + 3 < S_DIM) ? 1.0f : 0.0f;

    const float* base = lp + (size_t)b * C_DIM;

    // t=0 init (bit-identical)
    float a0 = 0.f, a1 = 0.f, a2 = 0.f, a3 = 0.f;
    {
        float i0 = __expf(base[0]);
        float i1v = __expf(base[c1]);
        if (lane == 0 && wave == 0) { a0 = i0; a1 = i1v; }
    }
    float ls = 0.f;

    // producer: 10 coalesced COMPILER loads, one anchor, one drain; exp whole
    // rows + ping-pong LDS store. Values bit-identical to baseline.
    auto produce = [&](int cc) {
        const int p = cc & 1;
        const int tstart = 1 + cc * CH;
        f32x4 v[RPW];
#pragma unroll
        for (int k = 0; k < RPW; ++k) {
            const int d = (wave - 1) + NPROD * k;
            if (d < CH) {
                int t = tstart + d; t = (t < ilen) ? t : (ilen - 1);
                v[k] = *(const f32x4*)(base + (size_t)t * rstride + (lane << 2));
            } else {
                v[k] = (f32x4){0.f, 0.f, 0.f, 0.f};
            }
        }
        asm volatile("" : "+v"(v[0]), "+v"(v[1]), "+v"(v[2]), "+v"(v[3]), "+v"(v[4]),
                          "+v"(v[5]), "+v"(v[6]), "+v"(v[7]), "+v"(v[8]), "+v"(v[9]));
#pragma unroll
        for (int k = 0; k < RPW; ++k) {
            const int d = (wave - 1) + NPROD * k;
            if (d < CH) {
                f32x4 e;
                e.x = __expf(v[k].x); e.y = __expf(v[k].y);
                e.z = __expf(v[k].z); e.w = __expf(v[k].w);
                *(f32x4*)&rows[p][d][lane << 2] = e;
            }
        }
    };

    // consumer step: inputs already exp'd; absmax must stay 96.0.
    auto step = [&](float pb, float p1e, float p3e) {
        const float p3 = DPP_F(a3, 0x138); // prev lane's a3; lane0 -> 0
        const float a01 = a0 + a1;
        const float n0 = (a0 + p3) * pb;
        const float n1 = fmaf(m1, p3, a01) * p1e;
        const float n2 = (a2 + a1) * pb;
        const float n3 = (fmaf(m3, a1, a2) + a3) * p3e;
        a0 = n0; a1 = n1; a2 = n2; a3 = n3;
    };

#define RENORM() do {                                                       \
        a0 *= f0; a1 *= f1; a2 *= f2; a3 *= f3;                             \
        const float mx = wave_max_dpp(fmaxf(fmaxf(a0, a1), fmaxf(a2, a3))); \
        const float inv = __builtin_amdgcn_rcpf(mx);                        \
        ls -= __logf(inv);                                                  \
        a0 *= inv; a1 *= inv; a2 *= inv; a3 *= inv;                         \
    } while (0)

    // consume chunk cc; renorms at t%8==0 (same set as all passing rounds:
    // full chunks at d&7==7 -> t<=960; tail in-guard -> 968..992).
    auto consume = [&](int cc) {
        const int p = cc & 1;
        const int tstart = 1 + cc * CH;
        if (tstart + CH <= ilen) {
            const uint32_t lbase =
                (uint32_t)(uintptr_t)(&rows[0][0][0]) + (uint32_t)(p * (CH * C_DIM * 4));
            uint32_t apb = lbase;                          // rows[p][d][0]
            uint32_t aq1 = lbase + ((uint32_t)c1 << 2);    // rows[p][d][c1]
            uint32_t aq3 = lbase + ((uint32_t)c3 << 2);    // rows[p][d][c3]
            float pb0, pb1, pb2, pb3, pb4;
            float qa0, qa1, qa2, qa3, qa4;
            float qb0, qb1, qb2, qb3, qb4;
            // prologue: steps 0..4 in flight (15 DS ops = lgkmcnt cap)
            ISS(0, "0"); ISS(1, "1024"); ISS(2, "2048"); ISS(3, "3072"); ISS(4, "4096");
            SD(0, "5120");              // d=0
            SD(1, "6144");              // d=1
            SD(2, "7168");              // d=2
            SD(3, "8192");              // d=3
            SD(4, "9216");              // d=4
            SD(0, "10240");             // d=5
            SD(1, "11264");             // d=6
            SD(2, "12288"); RENORM();   // d=7
            SD(3, "13312");             // d=8
            SD(4, "14336");             // d=9
            SD(0, "15360");             // d=10
            SD(1, "16384");             // d=11
            SD(2, "17408");             // d=12
            SD(3, "18432");             // d=13
            SD(4, "19456");             // d=14
            SD(0, "20480"); RENORM();   // d=15
            SD(1, "21504");             // d=16
            SD(2, "22528");             // d=17
            SD(3, "23552");             // d=18
            SD(4, "24576");             // d=19
            SD(0, "25600");             // d=20
            SD(1, "26624");             // d=21
            SD(2, "27648");             // d=22
            SD(3, "28672"); RENORM();   // d=23
            SD(4, "29696");             // d=24
            SD(0, "30720");             // d=25
            SD(1, "31744");             // d=26
            SD(2, "32768");             // d=27
            SD(3, "33792");             // d=28
            SD(4, "34816");             // d=29
            SD(0, "35840");             // d=30
            SD(1, "36864"); RENORM();   // d=31
            SD(2, "37888");             // d=32
            SD(3, "38912");             // d=33
            SD(4, "39936");             // d=34
            SD(0, "40960");             // d=35
            SD(1, "41984");             // d=36
            SD(2, "43008");             // d=37
            SD(3, "44032");             // d=38
            SD(4, "45056"); RENORM();   // d=39
            SD(0, "46080");             // d=40
            SD(1, "47104");             // d=41
            SD(2, "48128");             // d=42
            SD(3, "49152");             // d=43
            SD(4, "50176");             // d=44
            SD(0, "51200");             // d=45
            SD(1, "52224");             // d=46
            SD(2, "53248"); RENORM();   // d=47
            SD(3, "54272");             // d=48
            SD(4, "55296");             // d=49
            SD(0, "56320");             // d=50
            SD(1, "57344");             // d=51
            SD(2, "58368");             // d=52
            SD(3, "59392");             // d=53
            SD(4, "60416");             // d=54
            SD(0, "61440"); RENORM();   // d=55
            SD(1, "62464");             // d=56
            SD(2, "63488");             // d=57
            SD(3, "64512");             // d=58 (issues d=63)
            W("12"); STP(4);            // d=59
            W("9");  STP(0);            // d=60
            W("6");  STP(1);            // d=61
            W("3");  STP(2);            // d=62
            W("0");  STP(3); RENORM();  // d=63
        } else {
            // tail chunk (39 steps for T=1000): point-of-use form; renorm
            // in-guard at d&7==7 -> t=968,976,984,992 (t=1000 guarded out)
#pragma unroll
            for (int d = 0; d < CH; ++d) {
                if (tstart + d < ilen) {
                    step(rows[p][d][0], rows[p][d][c1], rows[p][d][c3]);
                    if ((d & 7) == 7) RENORM();
                }
            }
        }
    };

    const int nchunks = (ilen - 1 + CH - 1) / CH;
    if (wave != 0) produce(0);
    __syncthreads();
    if (wave == 0) __builtin_amdgcn_s_setprio(1); // consumer is the critical chain
    for (int c = 0; c < nchunks; ++c) {
        if (wave != 0) produce(c + 1); // other parity; last iter clamped junk, never read
        else consume(c);
        __syncthreads();
    }
    if (wave == 0) __builtin_amdgcn_s_setprio(0);
#undef RENORM

    if (wave != 0) return;

    // final: ll = log(alpha[2tl] + alpha[2tl-1]) + ls   (consumer wave only)
    const int s_hi = 2 * tlen;
    const int s_lo = 2 * tlen - 1;
    const int slot_hi = s_hi & 3, lane_hi = min(s_hi >> 2, 63);
    const int slot_lo = s_lo & 3, lane_lo = min(s_lo >> 2, 63);
    float ch = (slot_hi == 0) ? a0 : (slot_hi == 1) ? a1 : (slot_hi == 2) ? a2 : a3;
    float cl = (slot_lo == 0) ? a0 : (slot_lo == 1) ? a1 : (slot_lo == 2) ? a2 : a3;
    const float vh = __shfl(ch, lane_hi, 64);
    const float vl = __shfl(cl, lane_lo, 64);
    if (lane == 0) {
        const float s = vh + vl;
        const float loss = (s > 0.f) ? -(__logf(s) + ls) : 0.0f; // zero_infinity
        ws_loss[b] = loss;
    }
}

// out = (sum_j focal_j / (B*L)) * (sum_b loss_b / B)
__global__ __launch_bounds__(256) void ctc_finalize(
        const float* __restrict__ ws_mean, const float* __restrict__ ws_loss,
        const int* __restrict__ tgt, float* __restrict__ out) {
    const int tid = threadIdx.x;
    float fsum = 0.f;
#pragma unroll
    for (int k = 0; k < (B_DIM * L_DIM) / 256; ++k) {
        const int j = tid + k * 256;
        const int b = j / L_DIM;
        const int c = tgt[j];
        const float p = ws_mean[b * C_DIM + c];
        const float w = 1.0f - p;
        fsum += w * w;
    }
    float lsum = (tid < B_DIM) ? ws_loss[tid] : 0.f;
#pragma unroll
    for (int off = 32; off > 0; off >>= 1) {
        fsum += __shfl_down(fsum, off, 64);
        lsum += __shfl_down(lsum, off, 64);
    }
    __shared__ float sf[4], sl[4];
    const int w = tid >> 6;
    if ((tid & 63) == 0) { sf[w] = fsum; sl[w] = lsum; }
    __syncthreads();
    if (tid == 0) {
        const float F = sf[0] + sf[1] + sf[2] + sf[3];
        const float Lo = sl[0] + sl[1] + sl[2] + sl[3];
        out[0] = (F / (float)(B_DIM * L_DIM)) * (Lo / (float)B_DIM);
    }
}

extern "C" void kernel_launch(void* const* d_in, const int* in_sizes, int n_in,
                              void* d_out, int out_size, void* d_ws, size_t ws_size,
                              hipStream_t stream) {
    const float* lp = (const float*)d_in[0];
    const int* tgt = (const int*)d_in[1];
    const int* il = (const int*)d_in[2];
    const int* tl = (const int*)d_in[3];
    float* ws_mean = (float*)d_ws;               // B*C floats (atomicAdd target)
    float* ws_loss = ws_mean + B_DIM * C_DIM;    // B floats

    hipMemsetAsync(ws_mean, 0, B_DIM * C_DIM * sizeof(float), stream);
    ctc_fused<<<dim3(B_DIM + MEAN_BLOCKS), dim3(512), 0, stream>>>(
        lp, tgt, il, tl, ws_mean, ws_loss);
    ctc_finalize<<<dim3(1), dim3(256), 0, stream>>>(ws_mean, ws_loss, tgt, (float*)d_out);
}

// Round 11
// 136.689 us; speedup vs baseline: 1.0904x; 1.0052x over previous
//
#include <hip/hip_runtime.h>
#include <cstdint>

#define T_DIM 1000
#define B_DIM 64
#define C_DIM 256
#define L_DIM 100
#define S_DIM (2 * L_DIM + 1) /* 201 */
#define CH 32                 /* steps per chunk (R10: CH=64 was neutral-worse; back to 32) */
#define NPROD 7               /* producer waves (block = 8 waves) */
#define RPW 5                 /* ceil(CH/NPROD) rows per producer wave */
#define EMW 132               /* emit row: [0..63]=q1 [64..127]=q3 [128]=pb, stride 132 */
#define MEAN_BLOCKS 192       /* 64 b x 3 T-slices; grid = 64+192 = 256 = #CUs */

typedef float f32x4 __attribute__((ext_vector_type(4)));

// DPP cross-lane (VALU-rate). wave_shr:1=0x138, row_shr:n=0x110|n,
// row_bcast:15=0x142, row_bcast:31=0x143. bound_ctrl=true -> invalid lanes read 0.
#define DPP_I(x, ctrl) __builtin_amdgcn_update_dpp(0, (x), (ctrl), 0xF, 0xF, true)
#define DPP_F(x, ctrl) __int_as_float(DPP_I(__float_as_int(x), (ctrl)))

// R10 theory: per-STEP cost, insensitive to all latency scheduling -> the CU's
// DS pipe is throughput-saturated (producer b128 writes + 64-lane random
// gathers every step). R10 fix: producers gather the ~130 NEEDED values per
// row DIRECTLY FROM GLOBAL (c1/c3 are per-lane constants), exp only those,
// write a compact conflict-free emit row. DS traffic/chunk: ~40 b128 writes +
// 64 conflicted gathers  ->  ~96 lane-linear b32 writes + 96 free reads.
// Consumer values/op-order/renorm set UNCHANGED (absmax must stay 96.0).
#define DSR(dst, addr, OFF) \
    asm volatile("ds_read_b32 %0, %1 offset:" OFF : "=v"(dst) : "v"(addr))
#define ISS(s, OFF) do { DSR(pb##s, apb, OFF); DSR(qa##s, aq1, OFF); DSR(qb##s, aq3, OFF); } while (0)
#define W(N) do { asm volatile("s_waitcnt lgkmcnt(" N ")"); __builtin_amdgcn_sched_barrier(0); } while (0)
#define STP(s) step(pb##s, qa##s, qb##s)
#define SD(s, OFF) do { W("12"); STP(s); ISS(s, OFF); } while (0)

// Wave-wide max of non-negative values; exact, order-independent.
__device__ __forceinline__ float wave_max_dpp(float x) {
    x = fmaxf(x, DPP_F(x, 0x111)); // row_shr:1
    x = fmaxf(x, DPP_F(x, 0x112)); // row_shr:2
    x = fmaxf(x, DPP_F(x, 0x114)); // row_shr:4
    x = fmaxf(x, DPP_F(x, 0x118)); // row_shr:8
    x = fmaxf(x, DPP_F(x, 0x142)); // row_bcast:15
    x = fmaxf(x, DPP_F(x, 0x143)); // row_bcast:31 -> lane 63 has wave max
    return __int_as_float(__builtin_amdgcn_readlane(__float_as_int(x), 63));
}

// Fused kernel, 512-thread blocks; grid = 256 = #CUs (1 block/CU).
//   blocks [0,B): CTC alpha recursion.
//     wave 0  = consumer: R4 asm LDS pipeline on the compact emit layout
//               (q1: lane-linear, q3: lane-linear+256B, pb: uniform bcast --
//               all bank-conflict-free by construction).
//     waves 1-7 = producers: per row, 3 scattered global dword loads
//               (rp[c1], rp[c3], rp[0]; L2/L3-served, issued a chunk ahead),
//               single anchor + drain, 3 exps/lane, 3 b32 emit writes.
//   blocks [B, B+192): mean pass, f32x4-vectorized (unchanged from R10).
__global__ __launch_bounds__(512, 1) void ctc_fused(
        const float* __restrict__ lp,       // (T,B,C)
        const int* __restrict__ tgt,        // (B*L,)
        const int* __restrict__ il,         // (B,)
        const int* __restrict__ tl,         // (B,)
        float* __restrict__ ws_mean,        // (B,C) zero-initialized
        float* __restrict__ ws_loss) {      // (B,)
    const int blk = blockIdx.x;
    const uint32_t rstride = B_DIM * C_DIM;

    if (blk >= B_DIM) {
        // ---- mean pass: block=(b, slice of T in {336,336,328}); 8 waves ----
        __shared__ float sums[8][C_DIM];
        const int mb = blk - B_DIM;
        const int b = mb / 3;
        const int slice = mb % 3;
        const int start = slice * 336;
        const int end = (slice == 2) ? T_DIM : start + 336; // (end-start)%8==0
        const int lane = threadIdx.x & 63;
        const int wv = threadIdx.x >> 6;        // 0..7
        const float* p = lp + (size_t)b * C_DIM + (lane << 2);
        f32x4 s = {0.f, 0.f, 0.f, 0.f};
        for (int t = start + wv; t < end; t += 8) {
            f32x4 v = *(const f32x4*)(p + (size_t)t * rstride);
            s.x += __expf(v.x); s.y += __expf(v.y);
            s.z += __expf(v.z); s.w += __expf(v.w);
        }
        *(f32x4*)&sums[wv][lane << 2] = s;
        __syncthreads();
        if (threadIdx.x < C_DIM) {
            const int c = threadIdx.x;
            float tot = sums[0][c] + sums[1][c] + sums[2][c] + sums[3][c]
                      + sums[4][c] + sums[5][c] + sums[6][c] + sums[7][c];
            atomicAdd(&ws_mean[b * C_DIM + c], tot * (1.0f / T_DIM));
        }
        return;
    }

    // ---- CTC pass ----
    __shared__ __align__(16) float emit[2][CH][EMW]; // compact exp'd, 33.8 KB

    const int tid = threadIdx.x;
    const int lane = tid & 63;
    const int wave = tid >> 6;
    const int b = blk;
    const int* trow = tgt + b * L_DIM;
    const int ilen = il[b];
    const int tlen = tl[b];

    const int i1 = 2 * lane;
    const int i3 = 2 * lane + 1;
    const int c1 = (i1 < L_DIM) ? trow[i1] : 0;
    const int c3 = (i3 < L_DIM) ? trow[i3] : 0;
    const int c1m = (i1 >= 1 && i1 - 1 < L_DIM) ? trow[i1 - 1] : -1;
    const float m1 = ((i1 >= 1) && (c1 != c1m)) ? 1.0f : 0.0f;
    const float m3 = (c3 != c1) ? 1.0f : 0.0f;

    // invalid states (s >= S) must be zeroed at each renorm
    const float f0 = (4 * lane + 0 < S_DIM) ? 1.0f : 0.0f;
    const float f1 = (4 * lane + 1 < S_DIM) ? 1.0f : 0.0f;
    const float f2 = (4 * lane + 2 < S_DIM) ? 1.0f : 0.0f;
    const float f3 = (4 * lane + 3 < S_DIM) ? 1.0f : 0.0f;

    const float* base = lp + (size_t)b * C_DIM;

    // t=0 init (bit-identical)
    float a0 = 0.f, a1 = 0.f, a2 = 0.f, a3 = 0.f;
    {
        float i0 = __expf(base[0]);
        float i1v = __expf(base[c1]);
        if (lane == 0 && wave == 0) { a0 = i0; a1 = i1v; }
    }
    float ls = 0.f;

    // producer: per row, 3 scattered COMPILER global loads (sound waits),
    // single anchor -> batch issue + one drain; exp ONLY the needed values
    // (same v_exp_f32 on same input bits as before -> identical results);
    // 3 conflict-free b32 emit writes.
    auto produce = [&](int cc) {
        const int p = cc & 1;
        const int tstart = 1 + cc * CH;
        const int w = wave - 1;
        float v1[RPW], v3[RPW], v0[RPW];
#pragma unroll
        for (int k = 0; k < RPW; ++k) {
            const int d = w + NPROD * k;
            if (d < CH) {
                int t = tstart + d; t = (t < ilen) ? t : (ilen - 1);
                const float* rp = base + (size_t)t * rstride;
                v1[k] = rp[c1];
                v3[k] = rp[c3];
                v0[k] = rp[0];
            } else {
                v1[k] = 0.f; v3[k] = 0.f; v0[k] = 0.f;
            }
        }
        asm volatile("" : "+v"(v1[0]), "+v"(v1[1]), "+v"(v1[2]), "+v"(v1[3]), "+v"(v1[4]),
                          "+v"(v3[0]), "+v"(v3[1]), "+v"(v3[2]), "+v"(v3[3]), "+v"(v3[4]),
                          "+v"(v0[0]), "+v"(v0[1]), "+v"(v0[2]), "+v"(v0[3]), "+v"(v0[4]));
#pragma unroll
        for (int k = 0; k < RPW; ++k) {
            const int d = w + NPROD * k;
            if (d < CH) {
                const float e1 = __expf(v1[k]);
                const float e3 = __expf(v3[k]);
                const float e0 = __expf(v0[k]);
                emit[p][d][lane] = e1;
                emit[p][d][64 + lane] = e3;
                if (lane == 0) emit[p][d][128] = e0;
            }
        }
    };

    // consumer step: inputs already exp'd; absmax must stay 96.0.
    auto step = [&](float pb, float p1e, float p3e) {
        const float p3 = DPP_F(a3, 0x138); // prev lane's a3; lane0 -> 0
        const float a01 = a0 + a1;
        const float n0 = (a0 + p3) * pb;
        const float n1 = fmaf(m1, p3, a01) * p1e;
        const float n2 = (a2 + a1) * pb;
        const float n3 = (fmaf(m3, a1, a2) + a3) * p3e;
        a0 = n0; a1 = n1; a2 = n2; a3 = n3;
    };

#define RENORM() do {                                                       \
        a0 *= f0; a1 *= f1; a2 *= f2; a3 *= f3;                             \
        const float mx = wave_max_dpp(fmaxf(fmaxf(a0, a1), fmaxf(a2, a3))); \
        const float inv = __builtin_amdgcn_rcpf(mx);                        \
        ls -= __logf(inv);                                                  \
        a0 *= inv; a1 *= inv; a2 *= inv; a3 *= inv;                         \
    } while (0)

    // consume chunk cc; renorms after d=7,15,23,31: EXACTLY the established
    // renorm set (t%8==0, last at t=992 for T=1000; tail chunk in-guard).
    // Emit-row addressing: q1 @ lbase+lane*4+d*528, q3 @ +256, pb @ lbase+512
    // (uniform -> broadcast). All reads conflict-free by construction.
    auto consume = [&](int cc) {
        const int p = cc & 1;
        const int tstart = 1 + cc * CH;
        if (tstart + CH <= ilen) {
            const uint32_t lbase =
                (uint32_t)(uintptr_t)(&emit[0][0][0]) + (uint32_t)(p * (CH * EMW * 4));
            uint32_t apb = lbase + 512;                    // emit[p][d][128] (uniform)
            uint32_t aq1 = lbase + ((uint32_t)lane << 2);  // emit[p][d][lane]
            uint32_t aq3 = aq1 + 256;                      // emit[p][d][64+lane]
            float pb0, pb1, pb2, pb3, pb4;
            float qa0, qa1, qa2, qa3, qa4;
            float qb0, qb1, qb2, qb3, qb4;
            // prologue: steps 0..4 in flight (15 DS ops = lgkmcnt cap)
            ISS(0, "0"); ISS(1, "528"); ISS(2, "1056"); ISS(3, "1584"); ISS(4, "2112");
            SD(0, "2640");              // d=0
            SD(1, "3168");              // d=1
            SD(2, "3696");              // d=2
            SD(3, "4224");              // d=3
            SD(4, "4752");              // d=4
            SD(0, "5280");              // d=5
            SD(1, "5808");              // d=6
            SD(2, "6336"); RENORM();    // d=7
            SD(3, "6864");              // d=8
            SD(4, "7392");              // d=9
            SD(0, "7920");              // d=10
            SD(1, "8448");              // d=11
            SD(2, "8976");              // d=12
            SD(3, "9504");              // d=13
            SD(4, "10032");             // d=14
            SD(0, "10560"); RENORM();   // d=15
            SD(1, "11088");             // d=16
            SD(2, "11616");             // d=17
            SD(3, "12144");             // d=18
            SD(4, "12672");             // d=19
            SD(0, "13200");             // d=20
            SD(1, "13728");             // d=21
            SD(2, "14256");             // d=22
            SD(3, "14784"); RENORM();   // d=23
            SD(4, "15312");             // d=24
            SD(0, "15840");             // d=25
            SD(1, "16368");             // d=26 (issues d=31)
            W("12"); STP(2);            // d=27
            W("9");  STP(3);            // d=28
            W("6");  STP(4);            // d=29
            W("3");  STP(0);            // d=30
            W("0");  STP(1); RENORM();  // d=31
        } else {
            // tail chunk (7 steps for T=1000): point-of-use form
#pragma unroll
            for (int d = 0; d < CH; ++d) {
                if (tstart + d < ilen) {
                    step(emit[p][d][128], emit[p][d][lane], emit[p][d][64 + lane]);
                    if ((d & 7) == 7) RENORM();
                }
            }
        }
    };

    const int nchunks = (ilen - 1 + CH - 1) / CH;
    if (wave != 0) produce(0);
    __syncthreads();
    if (wave == 0) __builtin_amdgcn_s_setprio(1); // consumer is the critical chain
    for (int c = 0; c < nchunks; ++c) {
        if (wave != 0) produce(c + 1); // other parity; last iter clamped junk, never read
        else consume(c);
        __syncthreads();
    }
    if (wave == 0) __builtin_amdgcn_s_setprio(0);
#undef RENORM

    if (wave != 0) return;

    // final: ll = log(alpha[2tl] + alpha[2tl-1]) + ls   (consumer wave only)
    const int s_hi = 2 * tlen;
    const int s_lo = 2 * tlen - 1;
    const int slot_hi = s_hi & 3, lane_hi = min(s_hi >> 2, 63);
    const int slot_lo = s_lo & 3, lane_lo = min(s_lo >> 2, 63);
    float ch = (slot_hi == 0) ? a0 : (slot_hi == 1) ? a1 : (slot_hi == 2) ? a2 : a3;
    float cl = (slot_lo == 0) ? a0 : (slot_lo == 1) ? a1 : (slot_lo == 2) ? a2 : a3;
    const float vh = __shfl(ch, lane_hi, 64);
    const float vl = __shfl(cl, lane_lo, 64);
    if (lane == 0) {
        const float s = vh + vl;
        const float loss = (s > 0.f) ? -(__logf(s) + ls) : 0.0f; // zero_infinity
        ws_loss[b] = loss;
    }
}

// out = (sum_j focal_j / (B*L)) * (sum_b loss_b / B)
__global__ __launch_bounds__(256) void ctc_finalize(
        const float* __restrict__ ws_mean, const float* __restrict__ ws_loss,
        const int* __restrict__ tgt, float* __restrict__ out) {
    const int tid = threadIdx.x;
    float fsum = 0.f;
#pragma unroll
    for (int k = 0; k < (B_DIM * L_DIM) / 256; ++k) {
        const int j = tid + k * 256;
        const int b = j / L_DIM;
        const int c = tgt[j];
        const float p = ws_mean[b * C_DIM + c];
        const float w = 1.0f - p;
        fsum += w * w;
    }
    float lsum = (tid < B_DIM) ? ws_loss[tid] : 0.f;
#pragma unroll
    for (int off = 32; off > 0; off >>= 1) {
        fsum += __shfl_down(fsum, off, 64);
        lsum += __shfl_down(lsum, off, 64);
    }
    __shared__ float sf[4], sl[4];
    const int w = tid >> 6;
    if ((tid & 63) == 0) { sf[w] = fsum; sl[w] = lsum; }
    __syncthreads();
    if (tid == 0) {
        const float F = sf[0] + sf[1] + sf[2] + sf[3];
        const float Lo = sl[0] + sl[1] + sl[2] + sl[3];
        out[0] = (F / (float)(B_DIM * L_DIM)) * (Lo / (float)B_DIM);
    }
}

extern "C" void kernel_launch(void* const* d_in, const int* in_sizes, int n_in,
                              void* d_out, int out_size, void* d_ws, size_t ws_size,
                              hipStream_t stream) {
    const float* lp = (const float*)d_in[0];
    const int* tgt = (const int*)d_in[1];
    const int* il = (const int*)d_in[2];
    const int* tl = (const int*)d_in[3];
    float* ws_mean = (float*)d_ws;               // B*C floats (atomicAdd target)
    float* ws_loss = ws_mean + B_DIM * C_DIM;    // B floats

    hipMemsetAsync(ws_mean, 0, B_DIM * C_DIM * sizeof(float), stream);
    ctc_fused<<<dim3(B_DIM + MEAN_BLOCKS), dim3(512), 0, stream>>>(
        lp, tgt, il, tl, ws_mean, ws_loss);
    ctc_finalize<<<dim3(1), dim3(256), 0, stream>>>(ws_mean, ws_loss, tgt, (float*)d_out);
}